// Round 16
// baseline (831.283 us; speedup 1.0000x reference)
//
#include <hip/hip_runtime.h>
#include <hip/hip_bf16.h>
#include <stdint.h>

typedef short short8 __attribute__((ext_vector_type(8)));   // 8 bf16 (4 VGPRs)
typedef float f32x4 __attribute__((ext_vector_type(4)));

#define NSAMP 65536
#define AS1 __attribute__((address_space(1)))
#define AS3 __attribute__((address_space(3)))

__device__ __forceinline__ unsigned f2bf(float f) {
    union { float f; unsigned u; } v; v.f = f;
    unsigned u = v.u;
    u += 0x7fffu + ((u >> 16) & 1u);   // round-to-nearest-even
    return u >> 16;
}

__device__ __forceinline__ void wr8(char* d, f32x4 a, f32x4 b) {
    short8 o;
    o[0] = (short)f2bf(a[0]); o[1] = (short)f2bf(a[1]);
    o[2] = (short)f2bf(a[2]); o[3] = (short)f2bf(a[3]);
    o[4] = (short)f2bf(b[0]); o[5] = (short)f2bf(b[1]);
    o[6] = (short)f2bf(b[2]); o[7] = (short)f2bf(b[3]);
    *(short8*)d = o;
}

// ---------------- prep: COALESCED weight transposes + bias concat + y zero ----------------
struct PrepArgs {
    const float *W0, *W1, *W2, *A0, *C0, *A1, *C1, *a0v, *c0v;
    unsigned short *W0T, *W1T, *W2T, *RT0, *A1T, *C1T;
    float *bcat, *yout;
};
__device__ __forceinline__ void tr8(const float* __restrict__ W, unsigned short* __restrict__ WT,
                                    int N, int K, int n, int kb) {
    short8 o;
#pragma unroll
    for (int j = 0; j < 8; ++j) o[j] = (short)f2bf(W[(size_t)(kb * 8 + j) * N + n]);
    *(short8*)(WT + (size_t)n * K + kb * 8) = o;
}
__global__ void k_prep(PrepArgs p) {
    int i = blockIdx.x * blockDim.x + threadIdx.x;
    if (i < 65536)  { tr8(p.W0, p.W0T, 1024, 512,  i & 1023, i >> 10); return; }   // W0 512x1024
    i -= 65536;
    if (i < 131072) { tr8(p.W1, p.W1T, 1024, 1024, i & 1023, i >> 10); return; }   // W1 1024x1024
    i -= 131072;
    if (i < 65536)  { tr8(p.W2, p.W2T, 512, 1024,  i & 511,  i >> 9);  return; }   // W2 1024x512
    i -= 65536;
    if (i < 32768)  { tr8(p.A0, p.RT0, 512, 512,   i & 511,  i >> 9);  return; }   // A0 512x512
    i -= 32768;
    if (i < 32768)  { int n = i & 511; tr8(p.C0, p.RT0 + (size_t)512 * 512, 512, 512, n, i >> 9); return; }
    i -= 32768;
    if (i < 32768)  { tr8(p.A1, p.A1T, 512, 512,   i & 511,  i >> 9);  return; }
    i -= 32768;
    if (i < 32768)  { tr8(p.C1, p.C1T, 512, 512,   i & 511,  i >> 9);  return; }
    i -= 32768;
    if (i < 512)    { p.bcat[i] = p.a0v[i]; return; }
    i -= 512;
    if (i < 512)    { p.bcat[512 + i] = p.c0v[i]; return; }
    i -= 512;
    if (i < 65536)  { p.yout[i] = 0.f; return; }
}
#define PREP_TOTAL (65536 + 131072 + 65536 + 4 * 32768 + 512 + 512 + 65536)

// ---------------- GEMM: persistent 256-block, 256x256 tiles, BK=64, 16x16x32 MFMA ----
// MODE 0: relu -> bf16 packed (A via LDS, r13-verified path)
// MODE 1: fp32 float4 + bf16 packed (A via LDS)
// MODE 2: merged 2-expert risk-L1 + fused dot + treatment-predicated atomicAdd
// MODE 3: A = fp32 X, in-kernel convert (reg-stage -> ds_write); r14 A/B: best for G1
// MODE 4 (r16, new): A bf16 DIRECT global->VGPR (skips LDS; one b128/frag touches 16
//   full 64B lines; x4 cross-wave re-read absorbed by L1/L2/L3). B via LDS (32KB
//   blocks Bk0@+0, Bk1@+16384, dbuf at 32768; same 64B-row chunk^=(row>>1)&3 swizzle).
//   LDS traffic/K-step drops 256KB -> 96KB and runs CONCURRENTLY with A's L2 path.
//   One barrier/step: {A-frag loads; stage B(g+1)->dbuf; ds Bk0; MFMA kk0; ds Bk1;
//   MFMA kk1; vmcnt(0) (A consumed, B(g+1) had full-step flight); lgkm0; barrier}.
//   Overwrite-safe: buf X staged at step g+2 start; reads of X at g drained before
//   barrier(g); two barriers between. Epilogue = MODE-0 (relu bf16 packed).
// Tile->block: cls = bid%TPB fixes N-tile (MODE2: expert); mt = w + (256/TPB)*tau.
// MFMA swapped (mfma(b,a)): D m=lane&15, n=(lane>>4)*4+reg (verified r1-r15).
template<int MODE>
__global__ __launch_bounds__(512, 2)
void k_gemm256(const void* __restrict__ Av, int lda,
               const unsigned short* __restrict__ BT, const unsigned short* __restrict__ BT2,
               const float* __restrict__ bias, const float* __restrict__ bias2,
               unsigned short* __restrict__ Cbf, float* __restrict__ Cf32,
               const float* __restrict__ w2, const float* __restrict__ w2b,
               const int* __restrict__ TRt, float* __restrict__ ydot,
               int Ncols, int K, int TPB)
{
    __shared__ __align__(16) char lds[131072];

    const int tid  = threadIdx.x;
    const int lane = tid & 63;
    const int wid  = tid >> 6;       // 0..7
    const int wr   = wid >> 2;       // 0..1  -> A rows [wr*128, +128)
    const int wcn  = wid & 3;        // 0..3  -> B rows [wcn*64, +64)

    // chunked XCD map: XCD x owns logical ids [32x, 32x+32)
    const int bid = (int)((blockIdx.x & 7) * 32 + (blockIdx.x >> 3));
    const int cls = bid % TPB;
    const int w   = bid / TPB;
    const int MSTEP = 256 / TPB;     // mt(tau) = w + MSTEP*tau

    int n0e, cOff = 0, expert = 0;
    const unsigned short* Bsel = BT;
    if (MODE == 2) {
        expert = cls >> 1;
        n0e = (cls & 1) << 8;
        cOff = expert << 9;
        if (expert) Bsel = BT2;
    } else {
        n0e = cls << 8;
    }

    // staging source (gload_lds path): 4 threads/row, pre-swizzled chunk
    const int srow = tid >> 2;
    const int scs  = (tid & 3) ^ ((srow >> 1) & 3);
    const int ldst = wid * 1024;     // + lane*16 implicit

    const unsigned short* gB0 = Bsel + (size_t)(n0e + srow) * K + scs * 8;
    const unsigned short* gB1 = gB0 + (size_t)128 * K;

    const unsigned short* Ab = (const unsigned short*)Av;
    const float*          Af = (const float*)Av;
    const size_t dA = (size_t)MSTEP * 256 * lda;       // per-tau advance (elements)
    const unsigned short* cA0 = Ab + (size_t)((w << 8) + srow) * lda + cOff + scs * 8;
    const unsigned short* cA1 = cA0 + (size_t)128 * lda;
    const float* cF = Af + (size_t)((w << 8) + srow) * lda + scs * 8;

    // MODE4: per-lane A-frag base: row = block_m + wr*128 + (lane&15), k8 = (lane>>4)*8
    const unsigned short* gA4 = Ab + (size_t)((w << 8) + wr * 128 + (lane & 15)) * lda
                                   + ((lane >> 4) << 3);

#define STAGE_BLK(dbuf, blkoff, g0, g1, koff)                                            \
    do {                                                                                 \
        __builtin_amdgcn_global_load_lds((const AS1 void*)((g0) + (koff)),               \
                                         (AS3 void*)((dbuf) + (blkoff) + ldst), 16, 0, 0); \
        __builtin_amdgcn_global_load_lds((const AS1 void*)((g1) + (koff)),               \
                                         (AS3 void*)((dbuf) + (blkoff) + 8192 + ldst), 16, 0, 0); \
    } while (0)

    // ds_read offsets (loop-invariant)
    int aOff[8], bOff[4];
#pragma unroll
    for (int i = 0; i < 8; ++i) {
        int r = wr * 128 + i * 16 + (lane & 15);
        aOff[i] = r * 64 + ((((lane >> 4) ^ ((r >> 1) & 3))) << 4);
    }
#pragma unroll
    for (int j = 0; j < 4; ++j) {
        int r = wcn * 64 + j * 16 + (lane & 15);
        bOff[j] = r * 64 + ((((lane >> 4) ^ ((r >> 1) & 3))) << 4);
    }

    f32x4 acc[8][4];
#pragma unroll
    for (int i = 0; i < 8; ++i)
#pragma unroll
        for (int j = 0; j < 4; ++j) acc[i][j] = (f32x4)0.f;

    const int KT  = K >> 6;
    const int TOT = TPB * KT;

    if constexpr (MODE == 4) {
        // ================= MODE 4: A global-direct, B via LDS =================
        // prologue: stage B tile 0 (Bk0@0, Bk1@16384 of buf0)
        STAGE_BLK(lds, 0,     gB0, gB1, 0);
        STAGE_BLK(lds, 16384, gB0, gB1, 32);
        asm volatile("s_waitcnt vmcnt(0)" ::: "memory");
        __builtin_amdgcn_s_barrier();
        __builtin_amdgcn_sched_barrier(0);

        const unsigned short* wA = gA4;
        int g = 0;
        for (int tau = 0; tau < TPB; ++tau) {
            for (int t = 0; t < KT; ++t, ++g) {
                const char* sbuf = lds + (g & 1) * 32768;
                char* dbuf = lds + ((g + 1) & 1) * 32768;
                const bool st = (g + 1 < TOT);
                const bool inTile = (t + 1 < KT);
                const int koff0 = t << 6;
                const int koffn = inTile ? ((t + 1) << 6) : 0;

                // A frags for this step (16 x global b128; L2/L3-served, x4 wave reuse)
                short8 af0[8], af1[8];
#pragma unroll
                for (int i = 0; i < 8; ++i)
                    af0[i] = *(const short8*)(wA + (size_t)i * 16 * lda + koff0);
#pragma unroll
                for (int i = 0; i < 8; ++i)
                    af1[i] = *(const short8*)(wA + (size_t)i * 16 * lda + koff0 + 32);
                // stage next step's B
                if (st) {
                    STAGE_BLK(dbuf, 0,     gB0, gB1, koffn);
                    STAGE_BLK(dbuf, 16384, gB0, gB1, koffn + 32);
                }
                short8 bf[4];
#pragma unroll
                for (int j = 0; j < 4; ++j) bf[j] = *(const short8*)(sbuf + bOff[j]);
                __builtin_amdgcn_s_setprio(1);
#pragma unroll
                for (int i = 0; i < 8; ++i)
#pragma unroll
                    for (int j = 0; j < 4; ++j)
                        acc[i][j] = __builtin_amdgcn_mfma_f32_16x16x32_bf16(bf[j], af0[i], acc[i][j], 0, 0, 0);
                __builtin_amdgcn_s_setprio(0);
#pragma unroll
                for (int j = 0; j < 4; ++j) bf[j] = *(const short8*)(sbuf + 16384 + bOff[j]);
                __builtin_amdgcn_s_setprio(1);
#pragma unroll
                for (int i = 0; i < 8; ++i)
#pragma unroll
                    for (int j = 0; j < 4; ++j)
                        acc[i][j] = __builtin_amdgcn_mfma_f32_16x16x32_bf16(bf[j], af1[i], acc[i][j], 0, 0, 0);
                __builtin_amdgcn_s_setprio(0);
                // certify B(g+1) (full-step flight; A already consumed) + publish
                asm volatile("s_waitcnt vmcnt(0)" ::: "memory");
                asm volatile("s_waitcnt lgkmcnt(0)" ::: "memory");
                __builtin_amdgcn_sched_barrier(0);
                __builtin_amdgcn_s_barrier();
                __builtin_amdgcn_sched_barrier(0);
            }
            // epilogue (MODE-0 style: relu + packed bf16)
            const int m0 = (w + MSTEP * tau) << 8;
            const int nb = n0e + wcn * 64 + ((lane >> 4) << 2);
            f32x4 bv[4];
#pragma unroll
            for (int j = 0; j < 4; ++j) bv[j] = *(const f32x4*)(bias + nb + j * 16);
#pragma unroll
            for (int i = 0; i < 8; ++i) {
                const int m = m0 + wr * 128 + i * 16 + (lane & 15);
                unsigned short* pbc = Cbf + (size_t)m * Ncols + nb;
#pragma unroll
                for (int j = 0; j < 4; ++j) {
                    f32x4 v = acc[i][j] + bv[j];
#pragma unroll
                    for (int r = 0; r < 4; ++r) v[r] = fmaxf(v[r], 0.f);
                    unsigned long long pk =
                        (unsigned long long)(f2bf(v[0]) | (f2bf(v[1]) << 16)) |
                        ((unsigned long long)(f2bf(v[2]) | (f2bf(v[3]) << 16)) << 32);
                    *(unsigned long long*)(pbc + j * 16) = pk;
                }
            }
#pragma unroll
            for (int i = 0; i < 8; ++i)
#pragma unroll
                for (int j = 0; j < 4; ++j) acc[i][j] = (f32x4)0.f;
            wA += dA;
        }
        return;
    }

    // ================= MODES 0/1/2/3: r15 path (verified best) =================
    f32x4 xr0, xr1, xr2, xr3;   // MODE3: Ak0(g+1) fp32 in flight
    f32x4 yr0, yr1, yr2, yr3;   // MODE3: Ak1(g+1) fp32 in flight

    if constexpr (MODE == 3) {
        xr0 = *(const f32x4*)(cF);                xr1 = *(const f32x4*)(cF + 4);
        xr2 = *(const f32x4*)(cF + 128 * lda);    xr3 = *(const f32x4*)(cF + 128 * lda + 4);
        STAGE_BLK(lds, 32768, gB0, gB1, 0);
        __builtin_amdgcn_sched_barrier(0);
        yr0 = *(const f32x4*)(cF + 32);             yr1 = *(const f32x4*)(cF + 36);
        yr2 = *(const f32x4*)(cF + 128 * lda + 32); yr3 = *(const f32x4*)(cF + 128 * lda + 36);
        STAGE_BLK(lds, 49152, gB0, gB1, 32);
        __builtin_amdgcn_sched_barrier(0);
        wr8(lds + tid * 16, xr0, xr1);
        wr8(lds + 8192 + tid * 16, xr2, xr3);
        asm volatile("s_waitcnt vmcnt(6)" ::: "memory");
        asm volatile("s_waitcnt lgkmcnt(0)" ::: "memory");
    } else {
        STAGE_BLK(lds, 0,     cA0, cA1, 0);
        STAGE_BLK(lds, 32768, gB0, gB1, 0);
        STAGE_BLK(lds, 16384, cA0, cA1, 32);
        STAGE_BLK(lds, 49152, gB0, gB1, 32);
        asm volatile("s_waitcnt vmcnt(4)" ::: "memory");
    }
    __builtin_amdgcn_s_barrier();
    __builtin_amdgcn_sched_barrier(0);

    short8 pa[4], pb[4];
#pragma unroll
    for (int i = 0; i < 4; ++i) pa[i] = *(const short8*)(lds + aOff[i]);
#pragma unroll
    for (int j = 0; j < 4; ++j) pb[j] = *(const short8*)(lds + 32768 + bOff[j]);

    int g = 0;
    for (int tau = 0; tau < TPB; ++tau) {
        const unsigned short* nA0 = cA0 + dA;
        const unsigned short* nA1 = cA1 + dA;
        const float* nF = cF + dA;

        for (int t = 0; t < KT; ++t, ++g) {
            char* sbuf = lds + (g & 1) * 65536;
            char* dbuf = lds + ((g + 1) & 1) * 65536;
            const bool inTile = (t + 1 < KT);
            const bool st = (g + 1 < TOT);
            const unsigned short* sA0 = inTile ? cA0 : nA0;
            const unsigned short* sA1 = inTile ? cA1 : nA1;
            const float* sF = inTile ? cF : nF;
            const int koff = inTile ? ((t + 1) << 6) : 0;
            short8 xa[4];

            if constexpr (MODE == 3) {
                wr8(sbuf + 16384 + tid * 16, yr0, yr1);
                wr8(sbuf + 16384 + 8192 + tid * 16, yr2, yr3);
                if (st) {
                    xr0 = *(const f32x4*)(sF + koff);               xr1 = *(const f32x4*)(sF + koff + 4);
                    xr2 = *(const f32x4*)(sF + 128 * lda + koff);   xr3 = *(const f32x4*)(sF + 128 * lda + koff + 4);
                    STAGE_BLK(dbuf, 32768, gB0, gB1, koff);
                    __builtin_amdgcn_sched_barrier(0);
                }
            } else {
                if (st) {
                    STAGE_BLK(dbuf, 0,     sA0, sA1, koff);
                    STAGE_BLK(dbuf, 32768, gB0, gB1, koff);
                }
            }
#pragma unroll
            for (int i = 0; i < 4; ++i) xa[i] = *(const short8*)(sbuf + aOff[4 + i]);
            __builtin_amdgcn_s_setprio(1);
#pragma unroll
            for (int i = 0; i < 4; ++i)
#pragma unroll
                for (int j = 0; j < 4; ++j)
                    acc[i][j] = __builtin_amdgcn_mfma_f32_16x16x32_bf16(pb[j], pa[i], acc[i][j], 0, 0, 0);
            __builtin_amdgcn_s_setprio(0);

            __builtin_amdgcn_s_setprio(1);
#pragma unroll
            for (int i = 0; i < 4; ++i)
#pragma unroll
                for (int j = 0; j < 4; ++j)
                    acc[4 + i][j] = __builtin_amdgcn_mfma_f32_16x16x32_bf16(pb[j], xa[i], acc[4 + i][j], 0, 0, 0);
            __builtin_amdgcn_s_setprio(0);
            if (st) {
                if constexpr (MODE == 3) { asm volatile("s_waitcnt vmcnt(6)" ::: "memory"); }
                else                     { asm volatile("s_waitcnt vmcnt(4)" ::: "memory"); }
            } else {
                asm volatile("s_waitcnt vmcnt(0)" ::: "memory");
            }
            if constexpr (MODE == 3) { asm volatile("s_waitcnt lgkmcnt(0)" ::: "memory"); }
            __builtin_amdgcn_sched_barrier(0);
            __builtin_amdgcn_s_barrier();
            __builtin_amdgcn_sched_barrier(0);

#pragma unroll
            for (int i = 0; i < 4; ++i) pa[i] = *(const short8*)(sbuf + 16384 + aOff[i]);
#pragma unroll
            for (int j = 0; j < 4; ++j) pb[j] = *(const short8*)(sbuf + 49152 + bOff[j]);
            if constexpr (MODE == 3) {
                if (st) {
                    yr0 = *(const f32x4*)(sF + koff + 32);             yr1 = *(const f32x4*)(sF + koff + 36);
                    yr2 = *(const f32x4*)(sF + 128 * lda + koff + 32); yr3 = *(const f32x4*)(sF + 128 * lda + koff + 36);
                    STAGE_BLK(dbuf, 49152, gB0, gB1, koff + 32);
                    __builtin_amdgcn_sched_barrier(0);
                }
            } else {
                if (st) {
                    STAGE_BLK(dbuf, 16384, sA0, sA1, koff + 32);
                    STAGE_BLK(dbuf, 49152, gB0, gB1, koff + 32);
                }
            }
            __builtin_amdgcn_s_setprio(1);
#pragma unroll
            for (int i = 0; i < 4; ++i)
#pragma unroll
                for (int j = 0; j < 4; ++j)
                    acc[i][j] = __builtin_amdgcn_mfma_f32_16x16x32_bf16(pb[j], pa[i], acc[i][j], 0, 0, 0);
            __builtin_amdgcn_s_setprio(0);

#pragma unroll
            for (int i = 0; i < 4; ++i) xa[i] = *(const short8*)(sbuf + 16384 + aOff[4 + i]);
            __builtin_amdgcn_s_setprio(1);
#pragma unroll
            for (int i = 0; i < 4; ++i)
#pragma unroll
                for (int j = 0; j < 4; ++j)
                    acc[4 + i][j] = __builtin_amdgcn_mfma_f32_16x16x32_bf16(pb[j], xa[i], acc[4 + i][j], 0, 0, 0);
            __builtin_amdgcn_s_setprio(0);
            if (st) {
                if constexpr (MODE == 3) {
                    asm volatile("s_waitcnt vmcnt(6)" ::: "memory");
                    wr8(dbuf + tid * 16, xr0, xr1);
                    wr8(dbuf + 8192 + tid * 16, xr2, xr3);
                    asm volatile("s_waitcnt lgkmcnt(0)" ::: "memory");
                } else {
                    asm volatile("s_waitcnt vmcnt(4)" ::: "memory");
                }
                __builtin_amdgcn_sched_barrier(0);
                __builtin_amdgcn_s_barrier();
                __builtin_amdgcn_sched_barrier(0);
#pragma unroll
                for (int i = 0; i < 4; ++i) pa[i] = *(const short8*)(dbuf + aOff[i]);
#pragma unroll
                for (int j = 0; j < 4; ++j) pb[j] = *(const short8*)(dbuf + 32768 + bOff[j]);
            }
        }

        const int m0 = (w + MSTEP * tau) << 8;
        if (MODE == 2) {
            const float* be = expert ? bias2 : bias;
            const float* we = expert ? w2b : w2;
            const int nb = n0e + wcn * 64 + ((lane >> 4) << 2);
            f32x4 bv[4], wv[4];
#pragma unroll
            for (int j = 0; j < 4; ++j) {
                bv[j] = *(const f32x4*)(be + nb + j * 16);
                wv[j] = *(const f32x4*)(we + nb + j * 16);
            }
#pragma unroll
            for (int i = 0; i < 8; ++i) {
                float p = 0.f;
#pragma unroll
                for (int j = 0; j < 4; ++j)
#pragma unroll
                    for (int r = 0; r < 4; ++r)
                        p += fmaxf(acc[i][j][r] + bv[j][r], 0.f) * wv[j][r];
                p += __shfl_xor(p, 16);
                p += __shfl_xor(p, 32);
                const int m = m0 + wr * 128 + i * 16 + (lane & 15);
                if (lane < 16 && TRt[m] == expert) atomicAdd(&ydot[m], p);
            }
        } else {
            const int nb = n0e + wcn * 64 + ((lane >> 4) << 2);
            f32x4 bv[4];
#pragma unroll
            for (int j = 0; j < 4; ++j) bv[j] = *(const f32x4*)(bias + nb + j * 16);
#pragma unroll
            for (int i = 0; i < 8; ++i) {
                const int m = m0 + wr * 128 + i * 16 + (lane & 15);
                unsigned short* pbc = Cbf + (size_t)m * Ncols + nb;
#pragma unroll
                for (int j = 0; j < 4; ++j) {
                    f32x4 v = acc[i][j] + bv[j];
                    if (MODE != 1) {
#pragma unroll
                        for (int r = 0; r < 4; ++r) v[r] = fmaxf(v[r], 0.f);
                    }
                    if (MODE == 1) *(f32x4*)(Cf32 + (size_t)m * Ncols + nb + j * 16) = v;
                    unsigned long long pk =
                        (unsigned long long)(f2bf(v[0]) | (f2bf(v[1]) << 16)) |
                        ((unsigned long long)(f2bf(v[2]) | (f2bf(v[3]) << 16)) << 32);
                    *(unsigned long long*)(pbc + j * 16) = pk;
                }
            }
        }

#pragma unroll
        for (int i = 0; i < 8; ++i)
#pragma unroll
            for (int j = 0; j < 4; ++j) acc[i][j] = (f32x4)0.f;
        cA0 = nA0; cA1 = nA1; cF = nF;
    }
#undef STAGE_BLK
}

// ---------------- launch ----------------

extern "C" void kernel_launch(void* const* d_in, const int* in_sizes, int n_in,
                              void* d_out, int out_size, void* d_ws, size_t ws_size,
                              hipStream_t stream) {
    const float* X  = (const float*)d_in[0];
    const int*  TR  = (const int*)d_in[1];
    const float* W0 = (const float*)d_in[2];  const float* b0 = (const float*)d_in[3];
    const float* W1 = (const float*)d_in[4];  const float* b1 = (const float*)d_in[5];
    const float* W2 = (const float*)d_in[6];  const float* b2 = (const float*)d_in[7];
    const float* A0 = (const float*)d_in[8];  const float* a0 = (const float*)d_in[9];
    const float* A1 = (const float*)d_in[10]; const float* a1 = (const float*)d_in[11];
    const float* A2 = (const float*)d_in[12];
    const float* C0 = (const float*)d_in[13]; const float* c0 = (const float*)d_in[14];
    const float* C1 = (const float*)d_in[15]; const float* c1 = (const float*)d_in[16];
    const float* C2 = (const float*)d_in[17];

    float* y_out   = (float*)d_out;           // [N]
    float* out_out = (float*)d_out + NSAMP;   // [N][512] fp32

    char* ws = (char*)d_ws;
    size_t off = 0;
    auto alloc = [&](size_t bytes) -> char* {
        char* p = ws + off;
        off += (bytes + 255) & ~(size_t)255;
        return p;
    };
    unsigned short* H1b = (unsigned short*)alloc((size_t)NSAMP * 1024 * 2);
    unsigned short* H2b = (unsigned short*)alloc((size_t)NSAMP * 1024 * 2);
    unsigned short* OUTb = H1b;                       // H1b dead after L1 GEMM
    unsigned short* R01  = H2b;                       // [N][1024]
    unsigned short* W0T = (unsigned short*)alloc(512 * 1024 * 2);
    unsigned short* W1T = (unsigned short*)alloc(1024 * 1024 * 2);
    unsigned short* W2T = (unsigned short*)alloc(1024 * 512 * 2);
    unsigned short* RT0 = (unsigned short*)alloc(1024 * 512 * 2);   // [A0T; C0T]
    unsigned short* A1T = (unsigned short*)alloc(512 * 512 * 2);
    unsigned short* C1T = (unsigned short*)alloc(512 * 512 * 2);
    float* bcat = (float*)alloc(1024 * 4);

    PrepArgs pa;
    pa.W0 = W0; pa.W1 = W1; pa.W2 = W2; pa.A0 = A0; pa.C0 = C0; pa.A1 = A1; pa.C1 = C1;
    pa.a0v = a0; pa.c0v = c0;
    pa.W0T = W0T; pa.W1T = W1T; pa.W2T = W2T; pa.RT0 = RT0; pa.A1T = A1T; pa.C1T = C1T;
    pa.bcat = bcat; pa.yout = y_out;
    k_prep<<<(PREP_TOTAL + 255) / 256, 256, 0, stream>>>(pa);

    // shared MLP (persistent grid = 256 blocks, 1/CU)
    // G1: MODE 3 (fused fp32 convert — r14 A/B verified best)
    k_gemm256<3><<<256, 512, 0, stream>>>((const void*)X, 512, W0T, nullptr, b0, nullptr,
                                          H1b, nullptr, nullptr, nullptr, nullptr, nullptr,
                                          1024, 512, 4);
    // G2: MODE 4 (A global-direct experiment)
    k_gemm256<4><<<256, 512, 0, stream>>>((const void*)H1b, 1024, W1T, nullptr, b1, nullptr,
                                          H2b, nullptr, nullptr, nullptr, nullptr, nullptr,
                                          1024, 1024, 4);
    k_gemm256<1><<<256, 512, 0, stream>>>((const void*)H2b, 1024, W2T, nullptr, b2, nullptr,
                                          OUTb, out_out, nullptr, nullptr, nullptr, nullptr,
                                          512, 1024, 2);

    // G4: risk-L0 merged, MODE 4 (A global-direct experiment)
    k_gemm256<4><<<256, 512, 0, stream>>>((const void*)OUTb, 512, RT0, nullptr, bcat, nullptr,
                                          R01, nullptr, nullptr, nullptr, nullptr, nullptr,
                                          1024, 512, 4);

    // G5: risk-L1 merged + fused dot + treatment-predicated atomic (MODE 2, r15 path)
    k_gemm256<2><<<256, 512, 0, stream>>>((const void*)R01, 1024, A1T, C1T, a1, c1,
                                          nullptr, nullptr, A2, C2, TR, y_out,
                                          512, 512, 4);
}

// Round 17
// 559.596 us; speedup vs baseline: 1.4855x; 1.4855x over previous
//
#include <hip/hip_runtime.h>
#include <hip/hip_bf16.h>
#include <stdint.h>

typedef short short8 __attribute__((ext_vector_type(8)));   // 8 bf16 (4 VGPRs)
typedef float f32x4 __attribute__((ext_vector_type(4)));

#define NSAMP 65536
#define AS1 __attribute__((address_space(1)))
#define AS3 __attribute__((address_space(3)))

__device__ __forceinline__ unsigned f2bf(float f) {
    union { float f; unsigned u; } v; v.f = f;
    unsigned u = v.u;
    u += 0x7fffu + ((u >> 16) & 1u);   // round-to-nearest-even
    return u >> 16;
}

__device__ __forceinline__ void wr8(char* d, f32x4 a, f32x4 b) {
    short8 o;
    o[0] = (short)f2bf(a[0]); o[1] = (short)f2bf(a[1]);
    o[2] = (short)f2bf(a[2]); o[3] = (short)f2bf(a[3]);
    o[4] = (short)f2bf(b[0]); o[5] = (short)f2bf(b[1]);
    o[6] = (short)f2bf(b[2]); o[7] = (short)f2bf(b[3]);
    *(short8*)d = o;
}

// ---------------- prep: COALESCED weight transposes + bias concat + y zero ----------------
// r13-verified: one thread owns (n, 8-k block) of a [K][N]->[N][K] transpose: 8 reads,
// each wave-coalesced (64 lanes x 4B consecutive n = 256B), one packed short8 16B write.
struct PrepArgs {
    const float *W0, *W1, *W2, *A0, *C0, *A1, *C1, *a0v, *c0v;
    unsigned short *W0T, *W1T, *W2T, *RT0, *A1T, *C1T;
    float *bcat, *yout;
};
__device__ __forceinline__ void tr8(const float* __restrict__ W, unsigned short* __restrict__ WT,
                                    int N, int K, int n, int kb) {
    short8 o;
#pragma unroll
    for (int j = 0; j < 8; ++j) o[j] = (short)f2bf(W[(size_t)(kb * 8 + j) * N + n]);
    *(short8*)(WT + (size_t)n * K + kb * 8) = o;
}
__global__ void k_prep(PrepArgs p) {
    int i = blockIdx.x * blockDim.x + threadIdx.x;
    if (i < 65536)  { tr8(p.W0, p.W0T, 1024, 512,  i & 1023, i >> 10); return; }   // W0 512x1024
    i -= 65536;
    if (i < 131072) { tr8(p.W1, p.W1T, 1024, 1024, i & 1023, i >> 10); return; }   // W1 1024x1024
    i -= 131072;
    if (i < 65536)  { tr8(p.W2, p.W2T, 512, 1024,  i & 511,  i >> 9);  return; }   // W2 1024x512
    i -= 65536;
    if (i < 32768)  { tr8(p.A0, p.RT0, 512, 512,   i & 511,  i >> 9);  return; }   // A0 512x512
    i -= 32768;
    if (i < 32768)  { int n = i & 511; tr8(p.C0, p.RT0 + (size_t)512 * 512, 512, 512, n, i >> 9); return; }
    i -= 32768;
    if (i < 32768)  { tr8(p.A1, p.A1T, 512, 512,   i & 511,  i >> 9);  return; }
    i -= 32768;
    if (i < 32768)  { tr8(p.C1, p.C1T, 512, 512,   i & 511,  i >> 9);  return; }
    i -= 32768;
    if (i < 512)    { p.bcat[i] = p.a0v[i]; return; }
    i -= 512;
    if (i < 512)    { p.bcat[512 + i] = p.c0v[i]; return; }
    i -= 512;
    if (i < 65536)  { p.yout[i] = 0.f; return; }
}
#define PREP_TOTAL (65536 + 131072 + 65536 + 4 * 32768 + 512 + 512 + 65536)

// ---------------- GEMM: persistent 256-block, 256x256 tiles, BK=64, 16x16x32 MFMA ----
// FINAL (r17 = r15 = r13 config; measured best 554-555us, reproduced twice).
// Persistent 2-barrier reg-prefetch pipeline; LDS 2 dbuf x {Ak0|Ak1|Bk0|Bk1}, 64B rows,
// chunk^=(row>>1)&3 via pre-swizzled global source; counted vmcnt never 0 mid-loop.
// MODE 0: relu -> bf16 packed; MODE 1: fp32 float4 + bf16 packed; MODE 2: merged
// 2-expert risk-L1 + fused dot + treatment-predicated atomicAdd; MODE 3: A = fp32 X
// with in-kernel convert (reg-stage 2xf32x4 -> cvt -> ds_write to the linear slots).
// Session ledger: r14 A/B: MODE3 > separate convert+MODE0 (152 vs ~160us for G1+cvt).
// r16: A global-direct (skip LDS) = 2.3x WORSE (345us) — 64-line scatter per issue;
// LDS staging is the compressor, not the bottleneck's cause. Schedule variants
// (4-phase r3, persistent r5, 2-barrier r6, 32x32 r7, BK32 r9/r10, tri-buffer r11,
// unroll-2 r12) all plateau at 152-160us/GEMM: the 2-barrier-family ceiling.
// MODE3 vm accounting: P1 ds_write yr->sbuf.Ak1 (compiler waits Y: vmcnt(2), leaves
// Bk1(g):2); P2 vmcnt(6) certifies Bk1(g); P4 vmcnt(6) drains X+Bk0(g+1), ds_write xr,
// lgkm(0), barrier, prefetch. Tile->block: cls = bid%TPB fixes N-tile (MODE2: expert);
// mt = w + (256/TPB)*tau. MFMA swapped (mfma(b,a)): D m=lane&15, n=(lane>>4)*4+reg.
template<int MODE>
__global__ __launch_bounds__(512, 2)
void k_gemm256(const void* __restrict__ Av, int lda,
               const unsigned short* __restrict__ BT, const unsigned short* __restrict__ BT2,
               const float* __restrict__ bias, const float* __restrict__ bias2,
               unsigned short* __restrict__ Cbf, float* __restrict__ Cf32,
               const float* __restrict__ w2, const float* __restrict__ w2b,
               const int* __restrict__ TRt, float* __restrict__ ydot,
               int Ncols, int K, int TPB)
{
    __shared__ __align__(16) char lds[131072];

    const int tid  = threadIdx.x;
    const int lane = tid & 63;
    const int wid  = tid >> 6;       // 0..7
    const int wr   = wid >> 2;       // 0..1  -> A rows [wr*128, +128)
    const int wcn  = wid & 3;        // 0..3  -> B rows [wcn*64, +64)

    // chunked XCD map: XCD x owns logical ids [32x, 32x+32) -> A-panel sharers co-located
    const int bid = (int)((blockIdx.x & 7) * 32 + (blockIdx.x >> 3));
    const int cls = bid % TPB;
    const int w   = bid / TPB;
    const int MSTEP = 256 / TPB;     // mt stride per tau; mt(tau) = w + MSTEP*tau

    int n0e, cOff = 0, expert = 0;
    const unsigned short* Bsel = BT;
    if (MODE == 2) {
        expert = cls >> 1;
        n0e = (cls & 1) << 8;
        cOff = expert << 9;
        if (expert) Bsel = BT2;
    } else {
        n0e = cls << 8;
    }

    // per-thread staging source (row, pre-swizzled chunk)
    const int srow = tid >> 2;
    const int scs  = (tid & 3) ^ ((srow >> 1) & 3);
    const int ldst = wid * 1024;     // + lane*16 implicit

    const unsigned short* gB0 = Bsel + (size_t)(n0e + srow) * K + scs * 8;
    const unsigned short* gB1 = gB0 + (size_t)128 * K;

    // A source pointers: bf16 path (MODE<3) and fp32 path (MODE 3)
    const unsigned short* Ab = (const unsigned short*)Av;
    const float*          Af = (const float*)Av;
    const size_t dA = (size_t)MSTEP * 256 * lda;       // per-tau advance (elements)
    const unsigned short* cA0 = Ab + (size_t)((w << 8) + srow) * lda + cOff + scs * 8;
    const unsigned short* cA1 = cA0 + (size_t)128 * lda;
    const float* cF = Af + (size_t)((w << 8) + srow) * lda + scs * 8;   // fp32, second half at +128*lda

#define STAGE_BLK(dbuf, blkoff, g0, g1, koff)                                            \
    do {                                                                                 \
        __builtin_amdgcn_global_load_lds((const AS1 void*)((g0) + (koff)),               \
                                         (AS3 void*)((dbuf) + (blkoff) + ldst), 16, 0, 0); \
        __builtin_amdgcn_global_load_lds((const AS1 void*)((g1) + (koff)),               \
                                         (AS3 void*)((dbuf) + (blkoff) + 8192 + ldst), 16, 0, 0); \
    } while (0)

    // ds_read offsets (loop-invariant)
    int aOff[8], bOff[4];
#pragma unroll
    for (int i = 0; i < 8; ++i) {
        int r = wr * 128 + i * 16 + (lane & 15);
        aOff[i] = r * 64 + ((((lane >> 4) ^ ((r >> 1) & 3))) << 4);
    }
#pragma unroll
    for (int j = 0; j < 4; ++j) {
        int r = wcn * 64 + j * 16 + (lane & 15);
        bOff[j] = r * 64 + ((((lane >> 4) ^ ((r >> 1) & 3))) << 4);
    }

    f32x4 acc[8][4];
#pragma unroll
    for (int i = 0; i < 8; ++i)
#pragma unroll
        for (int j = 0; j < 4; ++j) acc[i][j] = (f32x4)0.f;

    const int KT  = K >> 6;
    const int TOT = TPB * KT;

    f32x4 xr0, xr1, xr2, xr3;   // MODE3: Ak0(g+1) fp32 in flight (loaded P1, written P4)
    f32x4 yr0, yr1, yr2, yr3;   // MODE3: Ak1(g+1) fp32 in flight (loaded P3, written P1(g+1))

    // ---- prologue: stage tile 0; certify Ak0,Bk0; prefetch regs
    if constexpr (MODE == 3) {
        xr0 = *(const f32x4*)(cF);                xr1 = *(const f32x4*)(cF + 4);
        xr2 = *(const f32x4*)(cF + 128 * lda);    xr3 = *(const f32x4*)(cF + 128 * lda + 4);
        STAGE_BLK(lds, 32768, gB0, gB1, 0);
        __builtin_amdgcn_sched_barrier(0);
        yr0 = *(const f32x4*)(cF + 32);             yr1 = *(const f32x4*)(cF + 36);
        yr2 = *(const f32x4*)(cF + 128 * lda + 32); yr3 = *(const f32x4*)(cF + 128 * lda + 36);
        STAGE_BLK(lds, 49152, gB0, gB1, 32);
        __builtin_amdgcn_sched_barrier(0);
        wr8(lds + tid * 16, xr0, xr1);
        wr8(lds + 8192 + tid * 16, xr2, xr3);
        asm volatile("s_waitcnt vmcnt(6)" ::: "memory");   // Bk0 landed (leaves Y4+Bk1:2)
        asm volatile("s_waitcnt lgkmcnt(0)" ::: "memory");
    } else {
        STAGE_BLK(lds, 0,     cA0, cA1, 0);
        STAGE_BLK(lds, 32768, gB0, gB1, 0);
        STAGE_BLK(lds, 16384, cA0, cA1, 32);
        STAGE_BLK(lds, 49152, gB0, gB1, 32);
        asm volatile("s_waitcnt vmcnt(4)" ::: "memory");
    }
    __builtin_amdgcn_s_barrier();
    __builtin_amdgcn_sched_barrier(0);

    short8 pa[4], pb[4];
#pragma unroll
    for (int i = 0; i < 4; ++i) pa[i] = *(const short8*)(lds + aOff[i]);
#pragma unroll
    for (int j = 0; j < 4; ++j) pb[j] = *(const short8*)(lds + 32768 + bOff[j]);

    int g = 0;
    for (int tau = 0; tau < TPB; ++tau) {
        const unsigned short* nA0 = cA0 + dA;   // next tau's A panel (B is tau-invariant)
        const unsigned short* nA1 = cA1 + dA;
        const float* nF = cF + dA;

        for (int t = 0; t < KT; ++t, ++g) {
            char* sbuf = lds + (g & 1) * 65536;
            char* dbuf = lds + ((g + 1) & 1) * 65536;
            const bool inTile = (t + 1 < KT);
            const bool st = (g + 1 < TOT);
            const unsigned short* sA0 = inTile ? cA0 : nA0;
            const unsigned short* sA1 = inTile ? cA1 : nA1;
            const float* sF = inTile ? cF : nF;
            const int koff = inTile ? ((t + 1) << 6) : 0;
            short8 xa[4];

            // ---- P1: [M3: write Ak1(g)] stage Ak0,Bk0(g+1); read Ak0-hi; MFMA kk0-lo
            if constexpr (MODE == 3) {
                wr8(sbuf + 16384 + tid * 16, yr0, yr1);          // compiler waits Y loads
                wr8(sbuf + 16384 + 8192 + tid * 16, yr2, yr3);
                if (st) {
                    xr0 = *(const f32x4*)(sF + koff);               xr1 = *(const f32x4*)(sF + koff + 4);
                    xr2 = *(const f32x4*)(sF + 128 * lda + koff);   xr3 = *(const f32x4*)(sF + 128 * lda + koff + 4);
                    STAGE_BLK(dbuf, 32768, gB0, gB1, koff);
                    __builtin_amdgcn_sched_barrier(0);
                }
            } else {
                if (st) {
                    STAGE_BLK(dbuf, 0,     sA0, sA1, koff);
                    STAGE_BLK(dbuf, 32768, gB0, gB1, koff);
                }
            }
#pragma unroll
            for (int i = 0; i < 4; ++i) xa[i] = *(const short8*)(sbuf + aOff[4 + i]);
            __builtin_amdgcn_s_setprio(1);
#pragma unroll
            for (int i = 0; i < 4; ++i)
#pragma unroll
                for (int j = 0; j < 4; ++j)
                    acc[i][j] = __builtin_amdgcn_mfma_f32_16x16x32_bf16(pb[j], pa[i], acc[i][j], 0, 0, 0);
            __builtin_amdgcn_s_setprio(0);

            // ---- P2: MFMA kk0-hi; mid sync (certify Ak1,Bk1(g))
            __builtin_amdgcn_s_setprio(1);
#pragma unroll
            for (int i = 0; i < 4; ++i)
#pragma unroll
                for (int j = 0; j < 4; ++j)
                    acc[4 + i][j] = __builtin_amdgcn_mfma_f32_16x16x32_bf16(pb[j], xa[i], acc[4 + i][j], 0, 0, 0);
            __builtin_amdgcn_s_setprio(0);
            if (st) {
                if constexpr (MODE == 3) { asm volatile("s_waitcnt vmcnt(6)" ::: "memory"); }
                else                     { asm volatile("s_waitcnt vmcnt(4)" ::: "memory"); }
            } else {
                asm volatile("s_waitcnt vmcnt(0)" ::: "memory");
            }
            if constexpr (MODE == 3) { asm volatile("s_waitcnt lgkmcnt(0)" ::: "memory"); }
            __builtin_amdgcn_sched_barrier(0);
            __builtin_amdgcn_s_barrier();
            __builtin_amdgcn_sched_barrier(0);

            // ---- P3: read kk1 frags; [M3: load Ak1(g+1)] stage (Ak1,)Bk1(g+1); MFMA kk1-lo
#pragma unroll
            for (int i = 0; i < 4; ++i) pa[i] = *(const short8*)(sbuf + 16384 + aOff[i]);
#pragma unroll
            for (int j = 0; j < 4; ++j) pb[j] = *(const short8*)(sbuf + 49152 + bOff[j]);
            if constexpr (MODE == 3) {
                if (st) {
                    yr0 = *(const f32x4*)(sF + koff + 32);             yr1 = *(const f32x4*)(sF + koff + 36);
                    yr2 = *(const f32x4*)(sF + 128 * lda + koff + 32); yr3 = *(const f32x4*)(sF + 128 * lda + koff + 36);
                    STAGE_BLK(dbuf, 49152, gB0, gB1, koff + 32);
                    __builtin_amdgcn_sched_barrier(0);
                }
            } else {
                if (st) {
                    STAGE_BLK(dbuf, 16384, sA0, sA1, koff + 32);
                    STAGE_BLK(dbuf, 49152, gB0, gB1, koff + 32);
                }
            }
            __builtin_amdgcn_s_setprio(1);
#pragma unroll
            for (int i = 0; i < 4; ++i)
#pragma unroll
                for (int j = 0; j < 4; ++j)
                    acc[i][j] = __builtin_amdgcn_mfma_f32_16x16x32_bf16(pb[j], pa[i], acc[i][j], 0, 0, 0);
            __builtin_amdgcn_s_setprio(0);

            // ---- P4: read Ak1-hi; MFMA kk1-hi; end sync; [M3: write Ak0(g+1)] prefetch regs
#pragma unroll
            for (int i = 0; i < 4; ++i) xa[i] = *(const short8*)(sbuf + 16384 + aOff[4 + i]);
            __builtin_amdgcn_s_setprio(1);
#pragma unroll
            for (int i = 0; i < 4; ++i)
#pragma unroll
                for (int j = 0; j < 4; ++j)
                    acc[4 + i][j] = __builtin_amdgcn_mfma_f32_16x16x32_bf16(pb[j], xa[i], acc[4 + i][j], 0, 0, 0);
            __builtin_amdgcn_s_setprio(0);
            if (st) {
                if constexpr (MODE == 3) {
                    asm volatile("s_waitcnt vmcnt(6)" ::: "memory");   // drains X + Bk0(g+1)
                    wr8(dbuf + tid * 16, xr0, xr1);
                    wr8(dbuf + 8192 + tid * 16, xr2, xr3);
                    asm volatile("s_waitcnt lgkmcnt(0)" ::: "memory");
                } else {
                    asm volatile("s_waitcnt vmcnt(4)" ::: "memory");   // certify Ak0,Bk0(g+1)
                }
                __builtin_amdgcn_sched_barrier(0);
                __builtin_amdgcn_s_barrier();
                __builtin_amdgcn_sched_barrier(0);
#pragma unroll
                for (int i = 0; i < 4; ++i) pa[i] = *(const short8*)(dbuf + aOff[i]);
#pragma unroll
                for (int j = 0; j < 4; ++j) pb[j] = *(const short8*)(dbuf + 32768 + bOff[j]);
            }
        }

        // ---- epilogue for tile (mt(tau), cls). D: m = ..+(lane&15), n = ..+(lane>>4)*4+reg
        const int m0 = (w + MSTEP * tau) << 8;
        if (MODE == 2) {
            const float* be = expert ? bias2 : bias;
            const float* we = expert ? w2b : w2;
            const int nb = n0e + wcn * 64 + ((lane >> 4) << 2);
            f32x4 bv[4], wv[4];
#pragma unroll
            for (int j = 0; j < 4; ++j) {
                bv[j] = *(const f32x4*)(be + nb + j * 16);
                wv[j] = *(const f32x4*)(we + nb + j * 16);
            }
#pragma unroll
            for (int i = 0; i < 8; ++i) {
                float p = 0.f;
#pragma unroll
                for (int j = 0; j < 4; ++j)
#pragma unroll
                    for (int r = 0; r < 4; ++r)
                        p += fmaxf(acc[i][j][r] + bv[j][r], 0.f) * wv[j][r];
                p += __shfl_xor(p, 16);
                p += __shfl_xor(p, 32);
                const int m = m0 + wr * 128 + i * 16 + (lane & 15);
                if (lane < 16 && TRt[m] == expert) atomicAdd(&ydot[m], p);
            }
        } else {
            const int nb = n0e + wcn * 64 + ((lane >> 4) << 2);
            f32x4 bv[4];
#pragma unroll
            for (int j = 0; j < 4; ++j) bv[j] = *(const f32x4*)(bias + nb + j * 16);
#pragma unroll
            for (int i = 0; i < 8; ++i) {
                const int m = m0 + wr * 128 + i * 16 + (lane & 15);
                unsigned short* pbc = Cbf + (size_t)m * Ncols + nb;
#pragma unroll
                for (int j = 0; j < 4; ++j) {
                    f32x4 v = acc[i][j] + bv[j];
                    if (MODE != 1) {
#pragma unroll
                        for (int r = 0; r < 4; ++r) v[r] = fmaxf(v[r], 0.f);
                    }
                    if (MODE == 1) *(f32x4*)(Cf32 + (size_t)m * Ncols + nb + j * 16) = v;
                    unsigned long long pk =
                        (unsigned long long)(f2bf(v[0]) | (f2bf(v[1]) << 16)) |
                        ((unsigned long long)(f2bf(v[2]) | (f2bf(v[3]) << 16)) << 32);
                    *(unsigned long long*)(pbc + j * 16) = pk;
                }
            }
        }

        // reset accumulators, advance A panel
#pragma unroll
        for (int i = 0; i < 8; ++i)
#pragma unroll
            for (int j = 0; j < 4; ++j) acc[i][j] = (f32x4)0.f;
        cA0 = nA0; cA1 = nA1; cF = nF;
    }
#undef STAGE_BLK
}

// ---------------- launch ----------------

extern "C" void kernel_launch(void* const* d_in, const int* in_sizes, int n_in,
                              void* d_out, int out_size, void* d_ws, size_t ws_size,
                              hipStream_t stream) {
    const float* X  = (const float*)d_in[0];
    const int*  TR  = (const int*)d_in[1];
    const float* W0 = (const float*)d_in[2];  const float* b0 = (const float*)d_in[3];
    const float* W1 = (const float*)d_in[4];  const float* b1 = (const float*)d_in[5];
    const float* W2 = (const float*)d_in[6];  const float* b2 = (const float*)d_in[7];
    const float* A0 = (const float*)d_in[8];  const float* a0 = (const float*)d_in[9];
    const float* A1 = (const float*)d_in[10]; const float* a1 = (const float*)d_in[11];
    const float* A2 = (const float*)d_in[12];
    const float* C0 = (const float*)d_in[13]; const float* c0 = (const float*)d_in[14];
    const float* C1 = (const float*)d_in[15]; const float* c1 = (const float*)d_in[16];
    const float* C2 = (const float*)d_in[17];

    float* y_out   = (float*)d_out;           // [N]
    float* out_out = (float*)d_out + NSAMP;   // [N][512] fp32

    char* ws = (char*)d_ws;
    size_t off = 0;
    auto alloc = [&](size_t bytes) -> char* {
        char* p = ws + off;
        off += (bytes + 255) & ~(size_t)255;
        return p;
    };
    unsigned short* H1b = (unsigned short*)alloc((size_t)NSAMP * 1024 * 2);
    unsigned short* H2b = (unsigned short*)alloc((size_t)NSAMP * 1024 * 2);
    unsigned short* OUTb = H1b;                       // H1b dead after L1 GEMM
    unsigned short* R01  = H2b;                       // [N][1024]: cols 0-511 expert0, 512-1023 expert1
    unsigned short* W0T = (unsigned short*)alloc(512 * 1024 * 2);
    unsigned short* W1T = (unsigned short*)alloc(1024 * 1024 * 2);
    unsigned short* W2T = (unsigned short*)alloc(1024 * 512 * 2);
    unsigned short* RT0 = (unsigned short*)alloc(1024 * 512 * 2);   // [A0T; C0T]
    unsigned short* A1T = (unsigned short*)alloc(512 * 512 * 2);
    unsigned short* C1T = (unsigned short*)alloc(512 * 512 * 2);
    float* bcat = (float*)alloc(1024 * 4);

    // prep (coalesced weight transposes + bias concat + y zero)
    PrepArgs pa;
    pa.W0 = W0; pa.W1 = W1; pa.W2 = W2; pa.A0 = A0; pa.C0 = C0; pa.A1 = A1; pa.C1 = C1;
    pa.a0v = a0; pa.c0v = c0;
    pa.W0T = W0T; pa.W1T = W1T; pa.W2T = W2T; pa.RT0 = RT0; pa.A1T = A1T; pa.C1T = C1T;
    pa.bcat = bcat; pa.yout = y_out;
    k_prep<<<(PREP_TOTAL + 255) / 256, 256, 0, stream>>>(pa);

    // shared MLP (persistent grid = 256 blocks, 1/CU)
    // G1: MODE 3 (fused fp32 convert — r14 A/B verified best)
    k_gemm256<3><<<256, 512, 0, stream>>>((const void*)X, 512, W0T, nullptr, b0, nullptr,
                                          H1b, nullptr, nullptr, nullptr, nullptr, nullptr,
                                          1024, 512, 4);
    k_gemm256<0><<<256, 512, 0, stream>>>((const void*)H1b, 1024, W1T, nullptr, b1, nullptr,
                                          H2b, nullptr, nullptr, nullptr, nullptr, nullptr,
                                          1024, 1024, 4);
    k_gemm256<1><<<256, 512, 0, stream>>>((const void*)H2b, 1024, W2T, nullptr, b2, nullptr,
                                          OUTb, out_out, nullptr, nullptr, nullptr, nullptr,
                                          512, 1024, 2);

    // risk nets layer 0, both experts merged (N=1024)
    k_gemm256<0><<<256, 512, 0, stream>>>((const void*)OUTb, 512, RT0, nullptr, bcat, nullptr,
                                          R01, nullptr, nullptr, nullptr, nullptr, nullptr,
                                          1024, 512, 4);

    // risk nets layer 1, both experts in one dispatch + fused dot + treatment-predicated
    // atomic into y_out (zeroed by k_prep)
    k_gemm256<2><<<256, 512, 0, stream>>>((const void*)R01, 1024, A1T, C1T, a1, c1,
                                          nullptr, nullptr, A2, C2, TR, y_out,
                                          512, 512, 4);
}

// Round 18
// 543.651 us; speedup vs baseline: 1.5291x; 1.0293x over previous
//
#include <hip/hip_runtime.h>
#include <hip/hip_bf16.h>
#include <stdint.h>

typedef short short8 __attribute__((ext_vector_type(8)));   // 8 bf16 (4 VGPRs)
typedef float f32x4 __attribute__((ext_vector_type(4)));

#define NSAMP 65536
#define AS1 __attribute__((address_space(1)))
#define AS3 __attribute__((address_space(3)))

__device__ __forceinline__ unsigned f2bf(float f) {
    union { float f; unsigned u; } v; v.f = f;
    unsigned u = v.u;
    u += 0x7fffu + ((u >> 16) & 1u);   // round-to-nearest-even
    return u >> 16;
}

__device__ __forceinline__ void wr8(char* d, f32x4 a, f32x4 b) {
    short8 o;
    o[0] = (short)f2bf(a[0]); o[1] = (short)f2bf(a[1]);
    o[2] = (short)f2bf(a[2]); o[3] = (short)f2bf(a[3]);
    o[4] = (short)f2bf(b[0]); o[5] = (short)f2bf(b[1]);
    o[6] = (short)f2bf(b[2]); o[7] = (short)f2bf(b[3]);
    *(short8*)d = o;
}

// ---------------- prep: COALESCED weight transposes + bias concat + y zero ----------------
// r13-verified: one thread owns (n, 8-k block) of a [K][N]->[N][K] transpose: 8 reads,
// each wave-coalesced (64 lanes x 4B consecutive n = 256B), one packed short8 16B write.
struct PrepArgs {
    const float *W0, *W1, *W2, *A0, *C0, *A1, *C1, *a0v, *c0v;
    unsigned short *W0T, *W1T, *W2T, *RT0, *A1T, *C1T;
    float *bcat, *yout;
};
__device__ __forceinline__ void tr8(const float* __restrict__ W, unsigned short* __restrict__ WT,
                                    int N, int K, int n, int kb) {
    short8 o;
#pragma unroll
    for (int j = 0; j < 8; ++j) o[j] = (short)f2bf(W[(size_t)(kb * 8 + j) * N + n]);
    *(short8*)(WT + (size_t)n * K + kb * 8) = o;
}
__global__ void k_prep(PrepArgs p) {
    int i = blockIdx.x * blockDim.x + threadIdx.x;
    if (i < 65536)  { tr8(p.W0, p.W0T, 1024, 512,  i & 1023, i >> 10); return; }   // W0 512x1024
    i -= 65536;
    if (i < 131072) { tr8(p.W1, p.W1T, 1024, 1024, i & 1023, i >> 10); return; }   // W1 1024x1024
    i -= 131072;
    if (i < 65536)  { tr8(p.W2, p.W2T, 512, 1024,  i & 511,  i >> 9);  return; }   // W2 1024x512
    i -= 65536;
    if (i < 32768)  { tr8(p.A0, p.RT0, 512, 512,   i & 511,  i >> 9);  return; }   // A0 512x512
    i -= 32768;
    if (i < 32768)  { int n = i & 511; tr8(p.C0, p.RT0 + (size_t)512 * 512, 512, 512, n, i >> 9); return; }
    i -= 32768;
    if (i < 32768)  { tr8(p.A1, p.A1T, 512, 512,   i & 511,  i >> 9);  return; }
    i -= 32768;
    if (i < 32768)  { tr8(p.C1, p.C1T, 512, 512,   i & 511,  i >> 9);  return; }
    i -= 32768;
    if (i < 512)    { p.bcat[i] = p.a0v[i]; return; }
    i -= 512;
    if (i < 512)    { p.bcat[512 + i] = p.c0v[i]; return; }
    i -= 512;
    if (i < 65536)  { p.yout[i] = 0.f; return; }
}
#define PREP_TOTAL (65536 + 131072 + 65536 + 4 * 32768 + 512 + 512 + 65536)

// ---------------- GEMM: persistent 256-block, 256x256 tiles, BK=64, 16x16x32 MFMA ----
// Core = r13/r17 verified (0 bank conflicts, VGPR 124, no spill). 2-barrier reg-prefetch
// pipeline; LDS 2 dbuf x {Ak0|Ak1|Bk0|Bk1}, 64B rows, chunk^=(row>>1)&3 via pre-swizzled
// global source; counted vmcnt never 0 mid-loop.
// MODE 0: relu -> bf16 packed; MODE 1: fp32 float4 + bf16 packed; MODE 2: merged
// 2-expert risk-L1 + fused dot + treatment-predicated atomicAdd.
// MODE 3 (r18 REVISED): A = fp32 X with fused convert, full-step-deep A pipeline:
//   BOTH fp32 halves of A(g+1) (xr=Ak0, yr=Ak1) load in P1(g) (~3 phases flight);
//   all 4 wr8s land in DBUF in P4(g) — no same-step sbuf write->read chain (the r8-r17
//   MODE3 wrote Ak1(g) into SBUF at P1(g), consumed P3(g): per-step VALU/LDS serial
//   chain, measured 2x step time, MfmaUtil 18%).
//   vm accounting: P1 issues xr(4),yr(4),Bk0-stage(2)=10; P3 issues Bk1-stage(2).
//   P2 waits vmcnt(10) -> retires Bk1(g) (issued P3(g-1)). P4 waits vmcnt(2) ->
//   retires xr,yr,Bk0(g+1) (leaves Bk1(g+1):2); wr8 x4 -> dbuf; lgkm(0); barrier;
//   prefetch. Write-safety: dbuf(g+1)=buffer(g-1); all reads of it drained before
//   end-barrier(g-1), two barriers upstream of P1/P4 writes.
// Tile->block: cls = bid%TPB fixes N-tile (MODE2: expert); mt = w + (256/TPB)*tau.
// MFMA swapped (mfma(b,a)): D m=lane&15, n=(lane>>4)*4+reg (verified r1-r17).
template<int MODE>
__global__ __launch_bounds__(512, 2)
void k_gemm256(const void* __restrict__ Av, int lda,
               const unsigned short* __restrict__ BT, const unsigned short* __restrict__ BT2,
               const float* __restrict__ bias, const float* __restrict__ bias2,
               unsigned short* __restrict__ Cbf, float* __restrict__ Cf32,
               const float* __restrict__ w2, const float* __restrict__ w2b,
               const int* __restrict__ TRt, float* __restrict__ ydot,
               int Ncols, int K, int TPB)
{
    __shared__ __align__(16) char lds[131072];

    const int tid  = threadIdx.x;
    const int lane = tid & 63;
    const int wid  = tid >> 6;       // 0..7
    const int wr   = wid >> 2;       // 0..1  -> A rows [wr*128, +128)
    const int wcn  = wid & 3;        // 0..3  -> B rows [wcn*64, +64)

    // chunked XCD map: XCD x owns logical ids [32x, 32x+32) -> A-panel sharers co-located
    const int bid = (int)((blockIdx.x & 7) * 32 + (blockIdx.x >> 3));
    const int cls = bid % TPB;
    const int w   = bid / TPB;
    const int MSTEP = 256 / TPB;     // mt stride per tau; mt(tau) = w + MSTEP*tau

    int n0e, cOff = 0, expert = 0;
    const unsigned short* Bsel = BT;
    if (MODE == 2) {
        expert = cls >> 1;
        n0e = (cls & 1) << 8;
        cOff = expert << 9;
        if (expert) Bsel = BT2;
    } else {
        n0e = cls << 8;
    }

    // per-thread staging source (row, pre-swizzled chunk)
    const int srow = tid >> 2;
    const int scs  = (tid & 3) ^ ((srow >> 1) & 3);
    const int ldst = wid * 1024;     // + lane*16 implicit

    const unsigned short* gB0 = Bsel + (size_t)(n0e + srow) * K + scs * 8;
    const unsigned short* gB1 = gB0 + (size_t)128 * K;

    // A source pointers: bf16 path (MODE<3) and fp32 path (MODE 3)
    const unsigned short* Ab = (const unsigned short*)Av;
    const float*          Af = (const float*)Av;
    const size_t dA = (size_t)MSTEP * 256 * lda;       // per-tau advance (elements)
    const unsigned short* cA0 = Ab + (size_t)((w << 8) + srow) * lda + cOff + scs * 8;
    const unsigned short* cA1 = cA0 + (size_t)128 * lda;
    const float* cF = Af + (size_t)((w << 8) + srow) * lda + scs * 8;   // fp32, second half at +128*lda

#define STAGE_BLK(dbuf, blkoff, g0, g1, koff)                                            \
    do {                                                                                 \
        __builtin_amdgcn_global_load_lds((const AS1 void*)((g0) + (koff)),               \
                                         (AS3 void*)((dbuf) + (blkoff) + ldst), 16, 0, 0); \
        __builtin_amdgcn_global_load_lds((const AS1 void*)((g1) + (koff)),               \
                                         (AS3 void*)((dbuf) + (blkoff) + 8192 + ldst), 16, 0, 0); \
    } while (0)

    // ds_read offsets (loop-invariant)
    int aOff[8], bOff[4];
#pragma unroll
    for (int i = 0; i < 8; ++i) {
        int r = wr * 128 + i * 16 + (lane & 15);
        aOff[i] = r * 64 + ((((lane >> 4) ^ ((r >> 1) & 3))) << 4);
    }
#pragma unroll
    for (int j = 0; j < 4; ++j) {
        int r = wcn * 64 + j * 16 + (lane & 15);
        bOff[j] = r * 64 + ((((lane >> 4) ^ ((r >> 1) & 3))) << 4);
    }

    f32x4 acc[8][4];
#pragma unroll
    for (int i = 0; i < 8; ++i)
#pragma unroll
        for (int j = 0; j < 4; ++j) acc[i][j] = (f32x4)0.f;

    const int KT  = K >> 6;
    const int TOT = TPB * KT;

    f32x4 xr0, xr1, xr2, xr3;   // MODE3: Ak0(g+1) fp32 in flight (loaded P1, written P4)
    f32x4 yr0, yr1, yr2, yr3;   // MODE3: Ak1(g+1) fp32 in flight (loaded P1, written P4)

    // ---- prologue: stage tile 0; certify; prefetch regs
    if constexpr (MODE == 3) {
        f32x4 a0 = *(const f32x4*)(cF);                f32x4 a1p = *(const f32x4*)(cF + 4);
        f32x4 a2 = *(const f32x4*)(cF + 128 * lda);    f32x4 a3p = *(const f32x4*)(cF + 128 * lda + 4);
        f32x4 b0v = *(const f32x4*)(cF + 32);             f32x4 b1v = *(const f32x4*)(cF + 36);
        f32x4 b2v = *(const f32x4*)(cF + 128 * lda + 32); f32x4 b3v = *(const f32x4*)(cF + 128 * lda + 36);
        STAGE_BLK(lds, 32768, gB0, gB1, 0);
        STAGE_BLK(lds, 49152, gB0, gB1, 32);
        asm volatile("s_waitcnt vmcnt(4)" ::: "memory");   // 8 A-loads retired; B(4) in flight
        wr8(lds + tid * 16, a0, a1p);                      // Ak0(0)
        wr8(lds + 8192 + tid * 16, a2, a3p);
        wr8(lds + 16384 + tid * 16, b0v, b1v);             // Ak1(0)
        wr8(lds + 16384 + 8192 + tid * 16, b2v, b3v);
        asm volatile("s_waitcnt vmcnt(0)" ::: "memory");   // B(0) landed
        asm volatile("s_waitcnt lgkmcnt(0)" ::: "memory");
    } else {
        STAGE_BLK(lds, 0,     cA0, cA1, 0);
        STAGE_BLK(lds, 32768, gB0, gB1, 0);
        STAGE_BLK(lds, 16384, cA0, cA1, 32);
        STAGE_BLK(lds, 49152, gB0, gB1, 32);
        asm volatile("s_waitcnt vmcnt(4)" ::: "memory");
    }
    __builtin_amdgcn_s_barrier();
    __builtin_amdgcn_sched_barrier(0);

    short8 pa[4], pb[4];
#pragma unroll
    for (int i = 0; i < 4; ++i) pa[i] = *(const short8*)(lds + aOff[i]);
#pragma unroll
    for (int j = 0; j < 4; ++j) pb[j] = *(const short8*)(lds + 32768 + bOff[j]);

    int g = 0;
    for (int tau = 0; tau < TPB; ++tau) {
        const unsigned short* nA0 = cA0 + dA;   // next tau's A panel (B is tau-invariant)
        const unsigned short* nA1 = cA1 + dA;
        const float* nF = cF + dA;

        for (int t = 0; t < KT; ++t, ++g) {
            char* sbuf = lds + (g & 1) * 65536;
            char* dbuf = lds + ((g + 1) & 1) * 65536;
            const bool inTile = (t + 1 < KT);
            const bool st = (g + 1 < TOT);
            const unsigned short* sA0 = inTile ? cA0 : nA0;
            const unsigned short* sA1 = inTile ? cA1 : nA1;
            const float* sF = inTile ? cF : nF;
            const int koff = inTile ? ((t + 1) << 6) : 0;
            short8 xa[4];

            // ---- P1: [M3: load xr+yr(g+1)] stage Bk0/(Ak0,Bk0)(g+1); read Ak0-hi; MFMA kk0-lo
            if constexpr (MODE == 3) {
                if (st) {
                    xr0 = *(const f32x4*)(sF + koff);               xr1 = *(const f32x4*)(sF + koff + 4);
                    xr2 = *(const f32x4*)(sF + 128 * lda + koff);   xr3 = *(const f32x4*)(sF + 128 * lda + koff + 4);
                    yr0 = *(const f32x4*)(sF + koff + 32);             yr1 = *(const f32x4*)(sF + koff + 36);
                    yr2 = *(const f32x4*)(sF + 128 * lda + koff + 32); yr3 = *(const f32x4*)(sF + 128 * lda + koff + 36);
                    STAGE_BLK(dbuf, 32768, gB0, gB1, koff);
                    __builtin_amdgcn_sched_barrier(0);
                }
            } else {
                if (st) {
                    STAGE_BLK(dbuf, 0,     sA0, sA1, koff);
                    STAGE_BLK(dbuf, 32768, gB0, gB1, koff);
                }
            }
#pragma unroll
            for (int i = 0; i < 4; ++i) xa[i] = *(const short8*)(sbuf + aOff[4 + i]);
            __builtin_amdgcn_s_setprio(1);
#pragma unroll
            for (int i = 0; i < 4; ++i)
#pragma unroll
                for (int j = 0; j < 4; ++j)
                    acc[i][j] = __builtin_amdgcn_mfma_f32_16x16x32_bf16(pb[j], pa[i], acc[i][j], 0, 0, 0);
            __builtin_amdgcn_s_setprio(0);

            // ---- P2: MFMA kk0-hi; mid sync (certify Ak1,Bk1(g))
            __builtin_amdgcn_s_setprio(1);
#pragma unroll
            for (int i = 0; i < 4; ++i)
#pragma unroll
                for (int j = 0; j < 4; ++j)
                    acc[4 + i][j] = __builtin_amdgcn_mfma_f32_16x16x32_bf16(pb[j], xa[i], acc[4 + i][j], 0, 0, 0);
            __builtin_amdgcn_s_setprio(0);
            if (st) {
                if constexpr (MODE == 3) { asm volatile("s_waitcnt vmcnt(10)" ::: "memory"); }
                else                     { asm volatile("s_waitcnt vmcnt(4)" ::: "memory"); }
            } else {
                asm volatile("s_waitcnt vmcnt(0)" ::: "memory");
            }
            if constexpr (MODE == 3) { asm volatile("s_waitcnt lgkmcnt(0)" ::: "memory"); }
            __builtin_amdgcn_sched_barrier(0);
            __builtin_amdgcn_s_barrier();
            __builtin_amdgcn_sched_barrier(0);

            // ---- P3: read kk1 frags; stage (Ak1,)Bk1(g+1); MFMA kk1-lo
#pragma unroll
            for (int i = 0; i < 4; ++i) pa[i] = *(const short8*)(sbuf + 16384 + aOff[i]);
#pragma unroll
            for (int j = 0; j < 4; ++j) pb[j] = *(const short8*)(sbuf + 49152 + bOff[j]);
            if constexpr (MODE == 3) {
                if (st) {
                    STAGE_BLK(dbuf, 49152, gB0, gB1, koff + 32);
                    __builtin_amdgcn_sched_barrier(0);
                }
            } else {
                if (st) {
                    STAGE_BLK(dbuf, 16384, sA0, sA1, koff + 32);
                    STAGE_BLK(dbuf, 49152, gB0, gB1, koff + 32);
                }
            }
            __builtin_amdgcn_s_setprio(1);
#pragma unroll
            for (int i = 0; i < 4; ++i)
#pragma unroll
                for (int j = 0; j < 4; ++j)
                    acc[i][j] = __builtin_amdgcn_mfma_f32_16x16x32_bf16(pb[j], pa[i], acc[i][j], 0, 0, 0);
            __builtin_amdgcn_s_setprio(0);

            // ---- P4: read Ak1-hi; MFMA kk1-hi; end sync; [M3: wr8 Ak0+Ak1(g+1)->dbuf] prefetch
#pragma unroll
            for (int i = 0; i < 4; ++i) xa[i] = *(const short8*)(sbuf + 16384 + aOff[4 + i]);
            __builtin_amdgcn_s_setprio(1);
#pragma unroll
            for (int i = 0; i < 4; ++i)
#pragma unroll
                for (int j = 0; j < 4; ++j)
                    acc[4 + i][j] = __builtin_amdgcn_mfma_f32_16x16x32_bf16(pb[j], xa[i], acc[4 + i][j], 0, 0, 0);
            __builtin_amdgcn_s_setprio(0);
            if (st) {
                if constexpr (MODE == 3) {
                    asm volatile("s_waitcnt vmcnt(2)" ::: "memory");   // xr,yr,Bk0(g+1) retired
                    wr8(dbuf + tid * 16, xr0, xr1);                    // Ak0(g+1)
                    wr8(dbuf + 8192 + tid * 16, xr2, xr3);
                    wr8(dbuf + 16384 + tid * 16, yr0, yr1);            // Ak1(g+1)
                    wr8(dbuf + 16384 + 8192 + tid * 16, yr2, yr3);
                    asm volatile("s_waitcnt lgkmcnt(0)" ::: "memory");
                } else {
                    asm volatile("s_waitcnt vmcnt(4)" ::: "memory");   // certify Ak0,Bk0(g+1)
                }
                __builtin_amdgcn_sched_barrier(0);
                __builtin_amdgcn_s_barrier();
                __builtin_amdgcn_sched_barrier(0);
#pragma unroll
                for (int i = 0; i < 4; ++i) pa[i] = *(const short8*)(dbuf + aOff[i]);
#pragma unroll
                for (int j = 0; j < 4; ++j) pb[j] = *(const short8*)(dbuf + 32768 + bOff[j]);
            }
        }

        // ---- epilogue for tile (mt(tau), cls). D: m = ..+(lane&15), n = ..+(lane>>4)*4+reg
        const int m0 = (w + MSTEP * tau) << 8;
        if (MODE == 2) {
            const float* be = expert ? bias2 : bias;
            const float* we = expert ? w2b : w2;
            const int nb = n0e + wcn * 64 + ((lane >> 4) << 2);
            f32x4 bv[4], wv[4];
#pragma unroll
            for (int j = 0; j < 4; ++j) {
                bv[j] = *(const f32x4*)(be + nb + j * 16);
                wv[j] = *(const f32x4*)(we + nb + j * 16);
            }
#pragma unroll
            for (int i = 0; i < 8; ++i) {
                float p = 0.f;
#pragma unroll
                for (int j = 0; j < 4; ++j)
#pragma unroll
                    for (int r = 0; r < 4; ++r)
                        p += fmaxf(acc[i][j][r] + bv[j][r], 0.f) * wv[j][r];
                p += __shfl_xor(p, 16);
                p += __shfl_xor(p, 32);
                const int m = m0 + wr * 128 + i * 16 + (lane & 15);
                if (lane < 16 && TRt[m] == expert) atomicAdd(&ydot[m], p);
            }
        } else {
            const int nb = n0e + wcn * 64 + ((lane >> 4) << 2);
            f32x4 bv[4];
#pragma unroll
            for (int j = 0; j < 4; ++j) bv[j] = *(const f32x4*)(bias + nb + j * 16);
#pragma unroll
            for (int i = 0; i < 8; ++i) {
                const int m = m0 + wr * 128 + i * 16 + (lane & 15);
                unsigned short* pbc = Cbf + (size_t)m * Ncols + nb;
#pragma unroll
                for (int j = 0; j < 4; ++j) {
                    f32x4 v = acc[i][j] + bv[j];
                    if (MODE != 1) {
#pragma unroll
                        for (int r = 0; r < 4; ++r) v[r] = fmaxf(v[r], 0.f);
                    }
                    if (MODE == 1) *(f32x4*)(Cf32 + (size_t)m * Ncols + nb + j * 16) = v;
                    unsigned long long pk =
                        (unsigned long long)(f2bf(v[0]) | (f2bf(v[1]) << 16)) |
                        ((unsigned long long)(f2bf(v[2]) | (f2bf(v[3]) << 16)) << 32);
                    *(unsigned long long*)(pbc + j * 16) = pk;
                }
            }
        }

        // reset accumulators, advance A panel
#pragma unroll
        for (int i = 0; i < 8; ++i)
#pragma unroll
            for (int j = 0; j < 4; ++j) acc[i][j] = (f32x4)0.f;
        cA0 = nA0; cA1 = nA1; cF = nF;
    }
#undef STAGE_BLK
}

// ---------------- launch ----------------

extern "C" void kernel_launch(void* const* d_in, const int* in_sizes, int n_in,
                              void* d_out, int out_size, void* d_ws, size_t ws_size,
                              hipStream_t stream) {
    const float* X  = (const float*)d_in[0];
    const int*  TR  = (const int*)d_in[1];
    const float* W0 = (const float*)d_in[2];  const float* b0 = (const float*)d_in[3];
    const float* W1 = (const float*)d_in[4];  const float* b1 = (const float*)d_in[5];
    const float* W2 = (const float*)d_in[6];  const float* b2 = (const float*)d_in[7];
    const float* A0 = (const float*)d_in[8];  const float* a0 = (const float*)d_in[9];
    const float* A1 = (const float*)d_in[10]; const float* a1 = (const float*)d_in[11];
    const float* A2 = (const float*)d_in[12];
    const float* C0 = (const float*)d_in[13]; const float* c0 = (const float*)d_in[14];
    const float* C1 = (const float*)d_in[15]; const float* c1 = (const float*)d_in[16];
    const float* C2 = (const float*)d_in[17];

    float* y_out   = (float*)d_out;           // [N]
    float* out_out = (float*)d_out + NSAMP;   // [N][512] fp32

    char* ws = (char*)d_ws;
    size_t off = 0;
    auto alloc = [&](size_t bytes) -> char* {
        char* p = ws + off;
        off += (bytes + 255) & ~(size_t)255;
        return p;
    };
    unsigned short* H1b = (unsigned short*)alloc((size_t)NSAMP * 1024 * 2);
    unsigned short* H2b = (unsigned short*)alloc((size_t)NSAMP * 1024 * 2);
    unsigned short* OUTb = H1b;                       // H1b dead after L1 GEMM
    unsigned short* R01  = H2b;                       // [N][1024]: cols 0-511 expert0, 512-1023 expert1
    unsigned short* W0T = (unsigned short*)alloc(512 * 1024 * 2);
    unsigned short* W1T = (unsigned short*)alloc(1024 * 1024 * 2);
    unsigned short* W2T = (unsigned short*)alloc(1024 * 512 * 2);
    unsigned short* RT0 = (unsigned short*)alloc(1024 * 512 * 2);   // [A0T; C0T]
    unsigned short* A1T = (unsigned short*)alloc(512 * 512 * 2);
    unsigned short* C1T = (unsigned short*)alloc(512 * 512 * 2);
    float* bcat = (float*)alloc(1024 * 4);

    // prep (coalesced weight transposes + bias concat + y zero)
    PrepArgs pa;
    pa.W0 = W0; pa.W1 = W1; pa.W2 = W2; pa.A0 = A0; pa.C0 = C0; pa.A1 = A1; pa.C1 = C1;
    pa.a0v = a0; pa.c0v = c0;
    pa.W0T = W0T; pa.W1T = W1T; pa.W2T = W2T; pa.RT0 = RT0; pa.A1T = A1T; pa.C1T = C1T;
    pa.bcat = bcat; pa.yout = y_out;
    k_prep<<<(PREP_TOTAL + 255) / 256, 256, 0, stream>>>(pa);

    // shared MLP (persistent grid = 256 blocks, 1/CU)
    // G1: MODE 3 (fused fp32 convert, r18 deep-pipelined A path)
    k_gemm256<3><<<256, 512, 0, stream>>>((const void*)X, 512, W0T, nullptr, b0, nullptr,
                                          H1b, nullptr, nullptr, nullptr, nullptr, nullptr,
                                          1024, 512, 4);
    k_gemm256<0><<<256, 512, 0, stream>>>((const void*)H1b, 1024, W1T, nullptr, b1, nullptr,
                                          H2b, nullptr, nullptr, nullptr, nullptr, nullptr,
                                          1024, 1024, 4);
    k_gemm256<1><<<256, 512, 0, stream>>>((const void*)H2b, 1024, W2T, nullptr, b2, nullptr,
                                          OUTb, out_out, nullptr, nullptr, nullptr, nullptr,
                                          512, 1024, 2);

    // risk nets layer 0, both experts merged (N=1024)
    k_gemm256<0><<<256, 512, 0, stream>>>((const void*)OUTb, 512, RT0, nullptr, bcat, nullptr,
                                          R01, nullptr, nullptr, nullptr, nullptr, nullptr,
                                          1024, 512, 4);

    // risk nets layer 1, both experts in one dispatch + fused dot + treatment-predicated
    // atomic into y_out (zeroed by k_prep)
    k_gemm256<2><<<256, 512, 0, stream>>>((const void*)R01, 1024, A1T, C1T, a1, c1,
                                          nullptr, nullptr, A2, C2, TR, y_out,
                                          512, 512, 4);
}